// Round 1
// baseline (222.208 us; speedup 1.0000x reference)
//
#include <hip/hip_runtime.h>
#include <hip/hip_bf16.h>

#define N 8192
#define D 768
#define TEMP_INV 20.0f

typedef __attribute__((ext_vector_type(8))) short bf16x8;
typedef __attribute__((ext_vector_type(4))) float f32x4;

// Workspace layout:
//   [0,        32768)  : rowsum float[8192]   (zeroed by norm_kernel)
//   [32768,    65536)  : pos    float[8192]   (fully written by sim_kernel)
//   [65536, +12.6MB)   : xn bf16 [8192][768]

// ---------------------------------------------------------------------------
// Kernel 1: row L2-normalize fp32 -> bf16, zero rowsum.
// One block per row; 256 threads x 3 elements = 768.
__global__ __launch_bounds__(256) void norm_kernel(
    const float* __restrict__ x, unsigned short* __restrict__ xn,
    float* __restrict__ rowsum) {
  int row = blockIdx.x;
  int t = threadIdx.x;
  const float* xr = x + (size_t)row * D;
  float v0 = xr[t];
  float v1 = xr[t + 256];
  float v2 = xr[t + 512];
  float ss = v0 * v0 + v1 * v1 + v2 * v2;
#pragma unroll
  for (int m = 32; m; m >>= 1) ss += __shfl_xor(ss, m);
  __shared__ float wsum[4];
  if ((t & 63) == 0) wsum[t >> 6] = ss;
  __syncthreads();
  float tot = wsum[0] + wsum[1] + wsum[2] + wsum[3];
  float inv = 1.0f / fmaxf(sqrtf(tot), 1e-8f);
  unsigned short* xr_o = xn + (size_t)row * D;
  __hip_bfloat16 b0 = __float2bfloat16(v0 * inv);
  __hip_bfloat16 b1 = __float2bfloat16(v1 * inv);
  __hip_bfloat16 b2 = __float2bfloat16(v2 * inv);
  xr_o[t]       = *(unsigned short*)&b0;
  xr_o[t + 256] = *(unsigned short*)&b1;
  xr_o[t + 512] = *(unsigned short*)&b2;
  if (t == 0) rowsum[row] = 0.0f;
}

// ---------------------------------------------------------------------------
// Kernel 2: upper-triangle 128x128 tiles of S = Xn * Xn^T via bf16 MFMA,
// fused epilogue: e = exp(20*s - 20) (diag zeroed), row/col sums -> atomicAdd,
// positive-pair logit -> pos[row].
__global__ __launch_bounds__(256) void sim_kernel(
    const unsigned short* __restrict__ xn, float* __restrict__ rowsum,
    float* __restrict__ pos) {
  int bj = blockIdx.x;  // column block
  int bi = blockIdx.y;  // row block
  if (bi > bj) return;  // symmetry: only upper triangle

  __shared__ short As[128 * 64];
  __shared__ short Bs[128 * 64];

  int t = threadIdx.x;
  int w = t >> 6, lane = t & 63;
  int q = lane >> 4, cl = lane & 15;
  int wm = w >> 1, wn = w & 1;

  f32x4 acc[4][4] = {};

  // staging pointers: thread t loads 8 bf16 (16B) from row (t>>3), col (t&7)*8
  const unsigned short* Ag = xn + (size_t)(bi * 128 + (t >> 3)) * D + (t & 7) * 8;
  const unsigned short* Bg = xn + (size_t)(bj * 128 + (t >> 3)) * D + (t & 7) * 8;
  short* Asl = As + t * 8;  // byte offset t*16: contiguous in lane order
  short* Bsl = Bs + t * 8;

  for (int kc = 0; kc < 12; ++kc) {
    int k0 = kc * 64;
#pragma unroll
    for (int r = 0; r < 4; ++r) {
      __builtin_amdgcn_global_load_lds(
          (const __attribute__((address_space(1))) unsigned int*)(Ag + (size_t)r * 32 * D + k0),
          (__attribute__((address_space(3))) unsigned int*)(Asl + r * 2048), 16, 0, 0);
      __builtin_amdgcn_global_load_lds(
          (const __attribute__((address_space(1))) unsigned int*)(Bg + (size_t)r * 32 * D + k0),
          (__attribute__((address_space(3))) unsigned int*)(Bsl + r * 2048), 16, 0, 0);
    }
    __syncthreads();  // drains vmcnt before barrier -> LDS ready
#pragma unroll
    for (int ks = 0; ks < 2; ++ks) {
      int kk = ks * 32 + q * 8;
      bf16x8 a[4], b[4];
#pragma unroll
      for (int m = 0; m < 4; ++m)
        a[m] = *(const bf16x8*)(As + (wm * 64 + m * 16 + cl) * 64 + kk);
#pragma unroll
      for (int n = 0; n < 4; ++n)
        b[n] = *(const bf16x8*)(Bs + (wn * 64 + n * 16 + cl) * 64 + kk);
#pragma unroll
      for (int m = 0; m < 4; ++m)
#pragma unroll
        for (int n = 0; n < 4; ++n)
          acc[m][n] = __builtin_amdgcn_mfma_f32_16x16x32_bf16(a[m], b[n], acc[m][n], 0, 0, 0);
    }
    __syncthreads();  // compute done before next overwrite
  }

  // Epilogue. C/D layout: col = lane&15, row = (lane>>4)*4 + reg.
  int gi0 = bi * 128 + wm * 64;
  int gj0 = bj * 128 + wn * 64;
  bool offdiag = (bi != bj);

  float rowp[4][4] = {};  // [m][reg] partial row sums (per-lane, over its col)
  float colp[4] = {};     // [n] partial col sums (per-lane col, over rows)
#pragma unroll
  for (int m = 0; m < 4; ++m) {
#pragma unroll
    for (int n = 0; n < 4; ++n) {
#pragma unroll
      for (int r = 0; r < 4; ++r) {
        float s = acc[m][n][r];
        int row = gi0 + m * 16 + q * 4 + r;
        int col = gj0 + n * 16 + cl;
        float e = __expf(TEMP_INV * s - 20.0f);
        if (col == row) e = 0.0f;                        // diagonal excluded
        if (col == (row ^ 1)) pos[row] = TEMP_INV * s;   // positive-pair logit
        rowp[m][r] += e;
        colp[n] += e;
      }
    }
  }
  // reduce rowp across the 16 lanes sharing a quad (cols 0..15)
#pragma unroll
  for (int m = 0; m < 4; ++m) {
#pragma unroll
    for (int r = 0; r < 4; ++r) {
      float v = rowp[m][r];
      v += __shfl_xor(v, 1);
      v += __shfl_xor(v, 2);
      v += __shfl_xor(v, 4);
      v += __shfl_xor(v, 8);
      if (cl == 0) atomicAdd(&rowsum[gi0 + m * 16 + q * 4 + r], v);
    }
  }
  // symmetric contribution: column sums feed rows in the bj range
  if (offdiag) {
#pragma unroll
    for (int n = 0; n < 4; ++n) {
      float v = colp[n];
      v += __shfl_xor(v, 16);
      v += __shfl_xor(v, 32);
      if (q == 0) atomicAdd(&rowsum[gj0 + n * 16 + cl], v);
    }
  }
}

// ---------------------------------------------------------------------------
// Kernel 3: loss = mean_i (20 + log(rowsum[i]) - pos[i])
__global__ __launch_bounds__(256) void loss_kernel(
    const float* __restrict__ rowsum, const float* __restrict__ pos,
    float* __restrict__ out) {
  int t = threadIdx.x;
  float acc = 0.0f;
  for (int i = t; i < N; i += 256) acc += 20.0f + __logf(rowsum[i]) - pos[i];
#pragma unroll
  for (int m = 32; m; m >>= 1) acc += __shfl_xor(acc, m);
  __shared__ float wsum[4];
  if ((t & 63) == 0) wsum[t >> 6] = acc;
  __syncthreads();
  if (t == 0) out[0] = (wsum[0] + wsum[1] + wsum[2] + wsum[3]) / (float)N;
}

extern "C" void kernel_launch(void* const* d_in, const int* in_sizes, int n_in,
                              void* d_out, int out_size, void* d_ws, size_t ws_size,
                              hipStream_t stream) {
  const float* x = (const float*)d_in[0];
  float* rowsum = (float*)d_ws;
  float* pos = rowsum + N;
  unsigned short* xn = (unsigned short*)(pos + N);

  norm_kernel<<<N, 256, 0, stream>>>(x, xn, rowsum);
  dim3 g2(64, 64);
  sim_kernel<<<g2, 256, 0, stream>>>(xn, rowsum, pos);
  loss_kernel<<<1, 256, 0, stream>>>(rowsum, pos, (float*)d_out);
}

// Round 2
// 184.631 us; speedup vs baseline: 1.2035x; 1.2035x over previous
//
#include <hip/hip_runtime.h>
#include <hip/hip_bf16.h>

#define N 8192
#define D 768
#define TEMP_INV 20.0f

typedef __attribute__((ext_vector_type(8))) short bf16x8;
typedef __attribute__((ext_vector_type(4))) float f32x4;

// Workspace layout:
//   [0,        32768)  : rowsum float[8192]   (zeroed by norm_kernel)
//   [32768,    65536)  : pos    float[8192]   (fully written by sim_kernel)
//   [65536, +12.6MB)   : xn bf16 [8192][768]

// ---------------------------------------------------------------------------
// Kernel 1: row L2-normalize fp32 -> bf16, zero rowsum.
// One block per row; 384 threads x float2 = 768 elements.
__global__ __launch_bounds__(384) void norm_kernel(
    const float* __restrict__ x, unsigned int* __restrict__ xn,
    float* __restrict__ rowsum) {
  int row = blockIdx.x;
  int t = threadIdx.x;
  const float2* xr = (const float2*)(x + (size_t)row * D);
  float2 v = xr[t];
  float ss = v.x * v.x + v.y * v.y;
#pragma unroll
  for (int m = 32; m; m >>= 1) ss += __shfl_xor(ss, m);
  __shared__ float wsum[6];
  if ((t & 63) == 0) wsum[t >> 6] = ss;
  __syncthreads();
  float tot = wsum[0] + wsum[1] + wsum[2] + wsum[3] + wsum[4] + wsum[5];
  float inv = 1.0f / fmaxf(sqrtf(tot), 1e-8f);
  __hip_bfloat16 b0 = __float2bfloat16(v.x * inv);
  __hip_bfloat16 b1 = __float2bfloat16(v.y * inv);
  unsigned int packed = (unsigned int)*(unsigned short*)&b0 |
                        ((unsigned int)*(unsigned short*)&b1 << 16);
  xn[(size_t)row * (D / 2) + t] = packed;
  if (t == 0) rowsum[row] = 0.0f;
}

// ---------------------------------------------------------------------------
// Kernel 2: upper-triangle 128x128 tiles of S = Xn * Xn^T via bf16 MFMA.
// LDS layout XOR-swizzled: physical 16B chunk = logical_chunk ^ (row & 7),
// so fragment reads (row stride 128 B = bank wrap) spread across all banks.
// Fused epilogue: e = exp(20*s - 20), diag zeroed (bi==bj only), row/col
// sums -> atomicAdd, positive-pair logit -> pos[row].
__global__ __launch_bounds__(256) void sim_kernel(
    const unsigned short* __restrict__ xn, float* __restrict__ rowsum,
    float* __restrict__ pos) {
  // decode triangular linear index -> (bi, bj), bi <= bj, 64x64 tile grid
  int L = blockIdx.x;
  float f = (129.0f - sqrtf(16641.0f - 8.0f * (float)L)) * 0.5f;
  int bi = (int)f;
  // base(b) = 64b - b(b-1)/2
  while (64 * (bi + 1) - ((bi + 1) * bi) / 2 <= L) ++bi;
  while (64 * bi - (bi * (bi - 1)) / 2 > L) --bi;
  int bj = bi + (L - (64 * bi - (bi * (bi - 1)) / 2));

  __shared__ short As[128 * 64];
  __shared__ short Bs[128 * 64];

  int t = threadIdx.x;
  int w = t >> 6, lane = t & 63;
  int q = lane >> 4, cl = lane & 15;
  int wm = w >> 1, wn = w & 1;

  f32x4 acc[4][4] = {};

  // staging: thread t fills physical chunk (t&7) of row (t>>3)+32r; the
  // global source chunk is xor-swizzled so physical = logical ^ (row&7)
  int swz = (((t & 7) ^ ((t >> 3) & 7))) * 8;
  const unsigned short* Ag = xn + (size_t)(bi * 128 + (t >> 3)) * D + swz;
  const unsigned short* Bg = xn + (size_t)(bj * 128 + (t >> 3)) * D + swz;
  short* Asl = As + t * 8;  // 16B-contiguous in lane order (global_load_lds req)
  short* Bsl = Bs + t * 8;

  for (int kc = 0; kc < 12; ++kc) {
    int k0 = kc * 64;
#pragma unroll
    for (int r = 0; r < 4; ++r) {
      __builtin_amdgcn_global_load_lds(
          (const __attribute__((address_space(1))) unsigned int*)(Ag + (size_t)r * 32 * D + k0),
          (__attribute__((address_space(3))) unsigned int*)(Asl + r * 2048), 16, 0, 0);
      __builtin_amdgcn_global_load_lds(
          (const __attribute__((address_space(1))) unsigned int*)(Bg + (size_t)r * 32 * D + k0),
          (__attribute__((address_space(3))) unsigned int*)(Bsl + r * 2048), 16, 0, 0);
    }
    __syncthreads();
#pragma unroll
    for (int ks = 0; ks < 2; ++ks) {
      bf16x8 a[4], b[4];
#pragma unroll
      for (int m = 0; m < 4; ++m)
        a[m] = *(const bf16x8*)(As + (wm * 64 + m * 16 + cl) * 64 +
                                (((ks * 4 + q) ^ (cl & 7)) * 8));
#pragma unroll
      for (int n = 0; n < 4; ++n)
        b[n] = *(const bf16x8*)(Bs + (wn * 64 + n * 16 + cl) * 64 +
                                (((ks * 4 + q) ^ (cl & 7)) * 8));
#pragma unroll
      for (int m = 0; m < 4; ++m)
#pragma unroll
        for (int n = 0; n < 4; ++n)
          acc[m][n] = __builtin_amdgcn_mfma_f32_16x16x32_bf16(a[m], b[n], acc[m][n], 0, 0, 0);
    }
    __syncthreads();
  }

  // Epilogue. C/D layout: col = lane&15, row = (lane>>4)*4 + reg.
  int gi0 = bi * 128 + wm * 64;
  int gj0 = bj * 128 + wn * 64;

  float rowp[4][4] = {};  // [m][reg] per-lane partial row sums
  float colp[4] = {};     // [n] per-lane partial col sums

  if (bi == bj) {
    // diagonal block: mask diag, capture positive-pair logits
#pragma unroll
    for (int m = 0; m < 4; ++m)
#pragma unroll
      for (int n = 0; n < 4; ++n)
#pragma unroll
        for (int r = 0; r < 4; ++r) {
          float s = acc[m][n][r];
          int row = gi0 + m * 16 + q * 4 + r;
          int col = gj0 + n * 16 + cl;
          float e = __expf(TEMP_INV * s - 20.0f);
          if (col == row) e = 0.0f;
          if (col == (row ^ 1)) pos[row] = TEMP_INV * s;
          rowp[m][r] += e;
        }
  } else {
#pragma unroll
    for (int m = 0; m < 4; ++m)
#pragma unroll
      for (int n = 0; n < 4; ++n)
#pragma unroll
        for (int r = 0; r < 4; ++r) {
          float e = __expf(TEMP_INV * acc[m][n][r] - 20.0f);
          rowp[m][r] += e;
          colp[n] += e;
        }
  }

  // reduce row partials across the 16 lanes of each quad (cols 0..15)
#pragma unroll
  for (int m = 0; m < 4; ++m)
#pragma unroll
    for (int r = 0; r < 4; ++r) {
      float v = rowp[m][r];
      v += __shfl_xor(v, 1);
      v += __shfl_xor(v, 2);
      v += __shfl_xor(v, 4);
      v += __shfl_xor(v, 8);
      if (cl == 0) atomicAdd(&rowsum[gi0 + m * 16 + q * 4 + r], v);
    }
  // symmetric contribution: col sums feed rows in the bj range (off-diag only)
  if (bi != bj) {
#pragma unroll
    for (int n = 0; n < 4; ++n) {
      float v = colp[n];
      v += __shfl_xor(v, 16);
      v += __shfl_xor(v, 32);
      if (q == 0) atomicAdd(&rowsum[gj0 + n * 16 + cl], v);
    }
  }
}

// ---------------------------------------------------------------------------
// Kernel 3: loss = mean_i (20 + log(rowsum[i]) - pos[i]); one 1024-thread block
__global__ __launch_bounds__(1024) void loss_kernel(
    const float* __restrict__ rowsum, const float* __restrict__ pos,
    float* __restrict__ out) {
  int t = threadIdx.x;
  const float4* r4 = (const float4*)rowsum;
  const float4* p4 = (const float4*)pos;
  float acc = 0.0f;
#pragma unroll
  for (int it = 0; it < 2; ++it) {
    int i = t + it * 1024;
    float4 r = r4[i], p = p4[i];
    acc += 80.0f + __logf(r.x) + __logf(r.y) + __logf(r.z) + __logf(r.w)
           - p.x - p.y - p.z - p.w;
  }
#pragma unroll
  for (int m = 32; m; m >>= 1) acc += __shfl_xor(acc, m);
  __shared__ float wsum[16];
  if ((t & 63) == 0) wsum[t >> 6] = acc;
  __syncthreads();
  if (t == 0) {
    float tot = 0.0f;
#pragma unroll
    for (int i = 0; i < 16; ++i) tot += wsum[i];
    out[0] = tot / (float)N;
  }
}

extern "C" void kernel_launch(void* const* d_in, const int* in_sizes, int n_in,
                              void* d_out, int out_size, void* d_ws, size_t ws_size,
                              hipStream_t stream) {
  const float* x = (const float*)d_in[0];
  float* rowsum = (float*)d_ws;
  float* pos = rowsum + N;
  unsigned short* xn = (unsigned short*)(pos + N);

  norm_kernel<<<N, 384, 0, stream>>>(x, (unsigned int*)xn, rowsum);
  sim_kernel<<<2080, 256, 0, stream>>>(xn, rowsum, pos);
  loss_kernel<<<1, 1024, 0, stream>>>(rowsum, pos, (float*)d_out);
}

// Round 4
// 133.577 us; speedup vs baseline: 1.6635x; 1.3822x over previous
//
#include <hip/hip_runtime.h>
#include <hip/hip_bf16.h>

#define N 8192
#define D 768
#define TEMP_INV 20.0f
#define NTILES 2080   // 64x64 tile-grid upper triangle incl. diagonal

typedef __attribute__((ext_vector_type(4))) float f32x4;
typedef long long i64;

// Workspace layout (floats):
//   [0,   N)     rowsum   (zeroed by norm_kernel)
//   [N,  2N)     pos      (fully written by sim_kernel diag tiles)
//   [2N, 2N+16)  pad
//   [2N+16, ...) xn fp8-e4m3 [N][768] bytes

// ---------------------------------------------------------------------------
// Kernel 1: row L2-normalize fp32 -> fp8 e4m3. One row per wave (4 rows/block).
__global__ __launch_bounds__(256) void norm_kernel(
    const float* __restrict__ x, unsigned char* __restrict__ xn,
    float* __restrict__ rowsum) {
  int t = threadIdx.x, w = t >> 6, lane = t & 63;
  int row = blockIdx.x * 4 + w;
  const float4* xr = (const float4*)(x + (size_t)row * D);
  float4 v[3];
  v[0] = xr[lane];
  v[1] = xr[lane + 64];
  v[2] = xr[lane + 128];
  float ss = 0.0f;
#pragma unroll
  for (int i = 0; i < 3; ++i)
    ss += v[i].x * v[i].x + v[i].y * v[i].y + v[i].z * v[i].z + v[i].w * v[i].w;
#pragma unroll
  for (int m = 32; m; m >>= 1) ss += __shfl_xor(ss, m);
  float inv = 1.0f / fmaxf(sqrtf(ss), 1e-8f);
  unsigned int* xo = (unsigned int*)(xn + (size_t)row * D);
#pragma unroll
  for (int i = 0; i < 3; ++i) {
    int p = __builtin_amdgcn_cvt_pk_fp8_f32(v[i].x * inv, v[i].y * inv, 0, false);
    p = __builtin_amdgcn_cvt_pk_fp8_f32(v[i].z * inv, v[i].w * inv, p, true);
    xo[lane + 64 * i] = p;
  }
  if (t < 4) rowsum[blockIdx.x * 4 + t] = 0.0f;
}

// ---------------------------------------------------------------------------
// Kernel 2: upper-triangle 128x128 tiles of S = Xn * Xn^T via fp8 MFMA, BK=128.
// LDS rows are 128 B (8 x 16B units); physical unit = logical ^ (row & 7)
// (XOR swizzle -> 0 bank conflicts; staging swizzles the global source chunk
// since global_load_lds destination must stay lane-contiguous).
__global__ __launch_bounds__(256, 3) void sim_kernel(
    const unsigned char* __restrict__ xn, float* __restrict__ rowsum,
    float* __restrict__ pos) {
  // decode triangular linear index -> (bi, bj), bi <= bj, 64x64 tile grid
  int L = blockIdx.x;
  float f = (129.0f - sqrtf(16641.0f - 8.0f * (float)L)) * 0.5f;
  int bi = (int)f;
  while (64 * (bi + 1) - ((bi + 1) * bi) / 2 <= L) ++bi;
  while (64 * bi - (bi * (bi - 1)) / 2 > L) --bi;
  int bj = bi + (L - (64 * bi - (bi * (bi - 1)) / 2));

  __shared__ __align__(16) unsigned char As[128 * 128];  // 16 KB
  __shared__ __align__(16) unsigned char Bs[128 * 128];  // 16 KB

  int t = threadIdx.x;
  int w = t >> 6, lane = t & 63;
  int q = lane >> 4, cl = lane & 15;
  int wm = w >> 1, wn = w & 1;

  f32x4 acc[4][4] = {};

  // staging: thread t fills physical unit (t&7) of row (t>>3)+32*rr; source
  // logical unit = (t&7) ^ (row&7); row&7 == (t>>3)&7 for all rr (32%8==0)
  int ulog = (((t & 7) ^ ((t >> 3) & 7))) * 16;
  const unsigned char* Ab = xn + (size_t)(bi * 128 + (t >> 3)) * D + ulog;
  const unsigned char* Bb = xn + (size_t)(bj * 128 + (t >> 3)) * D + ulog;

  for (int kc = 0; kc < 6; ++kc) {
    int k0 = kc * 128;
#pragma unroll
    for (int rr = 0; rr < 4; ++rr) {
      __builtin_amdgcn_global_load_lds(
          (const __attribute__((address_space(1))) unsigned int*)(Ab + (size_t)(rr * 32) * D + k0),
          (__attribute__((address_space(3))) unsigned int*)(As + rr * 4096 + t * 16), 16, 0, 0);
      __builtin_amdgcn_global_load_lds(
          (const __attribute__((address_space(1))) unsigned int*)(Bb + (size_t)(rr * 32) * D + k0),
          (__attribute__((address_space(3))) unsigned int*)(Bs + rr * 4096 + t * 16), 16, 0, 0);
    }
    __syncthreads();
#pragma unroll
    for (int ks = 0; ks < 4; ++ks) {
      // lane reads 8B chunk c = ks*4+q of its rows; within-row offset
      // swizzled: phys_unit = (c>>1) ^ (row&7), row&7 == cl&7 (16%8==0)
      int c = ks * 4 + q;
      int off = (((c >> 1) ^ (cl & 7)) * 16) + (c & 1) * 8;
      i64 a[4], b[4];
#pragma unroll
      for (int m = 0; m < 4; ++m)
        a[m] = *(const i64*)(As + (wm * 64 + m * 16 + cl) * 128 + off);
#pragma unroll
      for (int n = 0; n < 4; ++n)
        b[n] = *(const i64*)(Bs + (wn * 64 + n * 16 + cl) * 128 + off);
#pragma unroll
      for (int m = 0; m < 4; ++m)
#pragma unroll
        for (int n = 0; n < 4; ++n)
          acc[m][n] = __builtin_amdgcn_mfma_f32_16x16x32_fp8_fp8(a[m], b[n], acc[m][n], 0, 0, 0);
    }
    __syncthreads();
  }

  // Epilogue. C/D layout: col = lane&15, row = (lane>>4)*4 + reg (dtype-indep).
  int gi0 = bi * 128 + wm * 64;
  int gj0 = bj * 128 + wn * 64;

  float rowp[4][4] = {};
  float colp[4] = {};

  if (bi == bj) {
#pragma unroll
    for (int m = 0; m < 4; ++m)
#pragma unroll
      for (int n = 0; n < 4; ++n)
#pragma unroll
        for (int r = 0; r < 4; ++r) {
          float s = acc[m][n][r];
          int row = gi0 + m * 16 + q * 4 + r;
          int col = gj0 + n * 16 + cl;
          float e = __expf(TEMP_INV * s - 20.0f);
          if (col == row) e = 0.0f;
          if (col == (row ^ 1)) pos[row] = TEMP_INV * s;
          rowp[m][r] += e;
        }
  } else {
#pragma unroll
    for (int m = 0; m < 4; ++m)
#pragma unroll
      for (int n = 0; n < 4; ++n)
#pragma unroll
        for (int r = 0; r < 4; ++r) {
          float e = __expf(TEMP_INV * acc[m][n][r] - 20.0f);
          rowp[m][r] += e;
          colp[n] += e;
        }
  }

#pragma unroll
  for (int m = 0; m < 4; ++m)
#pragma unroll
    for (int r = 0; r < 4; ++r) {
      float v = rowp[m][r];
      v += __shfl_xor(v, 1);
      v += __shfl_xor(v, 2);
      v += __shfl_xor(v, 4);
      v += __shfl_xor(v, 8);
      if (cl == 0) atomicAdd(&rowsum[gi0 + m * 16 + q * 4 + r], v);
    }
  if (bi != bj) {
#pragma unroll
    for (int n = 0; n < 4; ++n) {
      float v = colp[n];
      v += __shfl_xor(v, 16);
      v += __shfl_xor(v, 32);
      if (q == 0) atomicAdd(&rowsum[gj0 + n * 16 + cl], v);
    }
  }
}

// ---------------------------------------------------------------------------
// Kernel 3: loss = mean_i (20 + log(rowsum[i]) - pos[i]); one 1024-thread block
__global__ __launch_bounds__(1024) void loss_kernel(
    const float* __restrict__ rowsum, const float* __restrict__ pos,
    float* __restrict__ out) {
  int t = threadIdx.x;
  const float4* r4 = (const float4*)rowsum;
  const float4* p4 = (const float4*)pos;
  float acc = 0.0f;
#pragma unroll
  for (int it = 0; it < 2; ++it) {
    int i = t + it * 1024;
    float4 r = r4[i], p = p4[i];
    acc += 80.0f + __logf(r.x) + __logf(r.y) + __logf(r.z) + __logf(r.w)
           - p.x - p.y - p.z - p.w;
  }
#pragma unroll
  for (int m = 32; m; m >>= 1) acc += __shfl_xor(acc, m);
  __shared__ float wsum[16];
  if ((t & 63) == 0) wsum[t >> 6] = acc;
  __syncthreads();
  if (t == 0) {
    float tot = 0.0f;
#pragma unroll
    for (int i = 0; i < 16; ++i) tot += wsum[i];
    out[0] = tot / (float)N;
  }
}

extern "C" void kernel_launch(void* const* d_in, const int* in_sizes, int n_in,
                              void* d_out, int out_size, void* d_ws, size_t ws_size,
                              hipStream_t stream) {
  const float* x = (const float*)d_in[0];
  float* rowsum = (float*)d_ws;
  float* pos = rowsum + N;
  unsigned char* xn = (unsigned char*)(rowsum + 2 * N + 16);

  norm_kernel<<<N / 4, 256, 0, stream>>>(x, xn, rowsum);
  sim_kernel<<<NTILES, 256, 0, stream>>>(xn, rowsum, pos);
  loss_kernel<<<1, 1024, 0, stream>>>(rowsum, pos, (float*)d_out);
}

// Round 5
// 129.025 us; speedup vs baseline: 1.7222x; 1.0353x over previous
//
#include <hip/hip_runtime.h>
#include <hip/hip_bf16.h>

#define N 8192
#define D 768
#define TEMP_INV 20.0f
#define NTILES 2080   // 64x64 tile-grid upper triangle incl. diagonal

typedef __attribute__((ext_vector_type(4))) float f32x4;
typedef __attribute__((ext_vector_type(4))) int i32x4;
typedef __attribute__((ext_vector_type(8))) int i32x8;

#define SCALE1 0x7F7F7F7F  // e8m0 = 127 in all 4 bytes -> scale 1.0

// Workspace layout (floats):
//   [0,   N)     rowsum   (zeroed by norm_kernel)
//   [N,  2N)     pos      (fully written by sim_kernel diag tiles)
//   [2N, 2N+16)  pad
//   [2N+16, ...) xn fp8-e4m3 [N][768] bytes

// ---------------------------------------------------------------------------
// Kernel 1: row L2-normalize fp32 -> fp8 e4m3. One row per wave (4 rows/block).
__global__ __launch_bounds__(256) void norm_kernel(
    const float* __restrict__ x, unsigned char* __restrict__ xn,
    float* __restrict__ rowsum) {
  int t = threadIdx.x, w = t >> 6, lane = t & 63;
  int row = blockIdx.x * 4 + w;
  const float4* xr = (const float4*)(x + (size_t)row * D);
  float4 v[3];
  v[0] = xr[lane];
  v[1] = xr[lane + 64];
  v[2] = xr[lane + 128];
  float ss = 0.0f;
#pragma unroll
  for (int i = 0; i < 3; ++i)
    ss += v[i].x * v[i].x + v[i].y * v[i].y + v[i].z * v[i].z + v[i].w * v[i].w;
#pragma unroll
  for (int m = 32; m; m >>= 1) ss += __shfl_xor(ss, m);
  float inv = 1.0f / fmaxf(sqrtf(ss), 1e-8f);
  unsigned int* xo = (unsigned int*)(xn + (size_t)row * D);
#pragma unroll
  for (int i = 0; i < 3; ++i) {
    int p = __builtin_amdgcn_cvt_pk_fp8_f32(v[i].x * inv, v[i].y * inv, 0, false);
    p = __builtin_amdgcn_cvt_pk_fp8_f32(v[i].z * inv, v[i].w * inv, p, true);
    xo[lane + 64 * i] = p;
  }
  if (t < 4) rowsum[blockIdx.x * 4 + t] = 0.0f;
}

// ---------------------------------------------------------------------------
// Kernel 2: upper-triangle 128x128 tiles of S = Xn * Xn^T via MX-scaled fp8
// MFMA (K=128, scales=1.0 -> plain fp8 GEMM at 2x the non-scaled rate).
// LDS rows are 128 B (8 x 16B units); physical unit = logical ^ (row & 7).
// Fragment reads are ds_read_b128 (units 2q, 2q^1) -> round-2's proven
// zero-conflict quad pattern.
__global__ __launch_bounds__(256, 3) void sim_kernel(
    const unsigned char* __restrict__ xn, float* __restrict__ rowsum,
    float* __restrict__ pos) {
  // decode triangular linear index -> (bi, bj), bi <= bj, 64x64 tile grid
  int L = blockIdx.x;
  float f = (129.0f - sqrtf(16641.0f - 8.0f * (float)L)) * 0.5f;
  int bi = (int)f;
  while (64 * (bi + 1) - ((bi + 1) * bi) / 2 <= L) ++bi;
  while (64 * bi - (bi * (bi - 1)) / 2 > L) --bi;
  int bj = bi + (L - (64 * bi - (bi * (bi - 1)) / 2));

  __shared__ __align__(16) unsigned char As[128 * 128];  // 16 KB
  __shared__ __align__(16) unsigned char Bs[128 * 128];  // 16 KB

  int t = threadIdx.x;
  int w = t >> 6, lane = t & 63;
  int q = lane >> 4, cl = lane & 15;
  int wm = w >> 1, wn = w & 1;

  f32x4 acc[4][4] = {};

  // staging: thread t fills physical unit (t&7) of row (t>>3)+32*rr; source
  // logical unit = (t&7) ^ (row&7); row&7 == (t>>3)&7 for all rr (32%8==0)
  int ulog = (((t & 7) ^ ((t >> 3) & 7))) * 16;
  const unsigned char* Ab = xn + (size_t)(bi * 128 + (t >> 3)) * D + ulog;
  const unsigned char* Bb = xn + (size_t)(bj * 128 + (t >> 3)) * D + ulog;

  // fragment read offsets: lane needs bytes k = q*32 .. q*32+31 of its row,
  // i.e. logical units 2q, 2q+1; phys = logical ^ (row&7), row&7 == cl&7
  int off0 = ((2 * q) ^ (cl & 7)) * 16;  // second unit is off0 ^ 16

  for (int kc = 0; kc < 6; ++kc) {
    int k0 = kc * 128;
#pragma unroll
    for (int rr = 0; rr < 4; ++rr) {
      __builtin_amdgcn_global_load_lds(
          (const __attribute__((address_space(1))) unsigned int*)(Ab + (size_t)(rr * 32) * D + k0),
          (__attribute__((address_space(3))) unsigned int*)(As + rr * 4096 + t * 16), 16, 0, 0);
      __builtin_amdgcn_global_load_lds(
          (const __attribute__((address_space(1))) unsigned int*)(Bb + (size_t)(rr * 32) * D + k0),
          (__attribute__((address_space(3))) unsigned int*)(Bs + rr * 4096 + t * 16), 16, 0, 0);
    }
    __syncthreads();

    union Frag { i32x8 v8; struct { i32x4 lo, hi; } p; };
    Frag a[4], b[4];
#pragma unroll
    for (int m = 0; m < 4; ++m) {
      const unsigned char* base = As + (wm * 64 + m * 16 + cl) * 128;
      a[m].p.lo = *(const i32x4*)(base + off0);
      a[m].p.hi = *(const i32x4*)(base + (off0 ^ 16));
    }
#pragma unroll
    for (int n = 0; n < 4; ++n) {
      const unsigned char* base = Bs + (wn * 64 + n * 16 + cl) * 128;
      b[n].p.lo = *(const i32x4*)(base + off0);
      b[n].p.hi = *(const i32x4*)(base + (off0 ^ 16));
    }
#pragma unroll
    for (int m = 0; m < 4; ++m)
#pragma unroll
      for (int n = 0; n < 4; ++n)
        acc[m][n] = __builtin_amdgcn_mfma_scale_f32_16x16x128_f8f6f4(
            a[m].v8, b[n].v8, acc[m][n], 0, 0, 0, SCALE1, 0, SCALE1);
    __syncthreads();
  }

  // Epilogue. C/D layout: col = lane&15, row = (lane>>4)*4 + reg (shape-det.).
  int gi0 = bi * 128 + wm * 64;
  int gj0 = bj * 128 + wn * 64;

  float rowp[4][4] = {};
  float colp[4] = {};

  if (bi == bj) {
#pragma unroll
    for (int m = 0; m < 4; ++m)
#pragma unroll
      for (int n = 0; n < 4; ++n)
#pragma unroll
        for (int r = 0; r < 4; ++r) {
          float s = acc[m][n][r];
          int row = gi0 + m * 16 + q * 4 + r;
          int col = gj0 + n * 16 + cl;
          float e = __expf(TEMP_INV * s - 20.0f);
          if (col == row) e = 0.0f;
          if (col == (row ^ 1)) pos[row] = TEMP_INV * s;
          rowp[m][r] += e;
        }
  } else {
#pragma unroll
    for (int m = 0; m < 4; ++m)
#pragma unroll
      for (int n = 0; n < 4; ++n)
#pragma unroll
        for (int r = 0; r < 4; ++r) {
          float e = __expf(TEMP_INV * acc[m][n][r] - 20.0f);
          rowp[m][r] += e;
          colp[n] += e;
        }
  }

#pragma unroll
  for (int m = 0; m < 4; ++m)
#pragma unroll
    for (int r = 0; r < 4; ++r) {
      float v = rowp[m][r];
      v += __shfl_xor(v, 1);
      v += __shfl_xor(v, 2);
      v += __shfl_xor(v, 4);
      v += __shfl_xor(v, 8);
      if (cl == 0) atomicAdd(&rowsum[gi0 + m * 16 + q * 4 + r], v);
    }
  if (bi != bj) {
#pragma unroll
    for (int n = 0; n < 4; ++n) {
      float v = colp[n];
      v += __shfl_xor(v, 16);
      v += __shfl_xor(v, 32);
      if (q == 0) atomicAdd(&rowsum[gj0 + n * 16 + cl], v);
    }
  }
}

// ---------------------------------------------------------------------------
// Kernel 3: loss = mean_i (20 + log(rowsum[i]) - pos[i]); one 1024-thread block
__global__ __launch_bounds__(1024) void loss_kernel(
    const float* __restrict__ rowsum, const float* __restrict__ pos,
    float* __restrict__ out) {
  int t = threadIdx.x;
  const float4* r4 = (const float4*)rowsum;
  const float4* p4 = (const float4*)pos;
  float acc = 0.0f;
#pragma unroll
  for (int it = 0; it < 2; ++it) {
    int i = t + it * 1024;
    float4 r = r4[i], p = p4[i];
    acc += 80.0f + __logf(r.x) + __logf(r.y) + __logf(r.z) + __logf(r.w)
           - p.x - p.y - p.z - p.w;
  }
#pragma unroll
  for (int m = 32; m; m >>= 1) acc += __shfl_xor(acc, m);
  __shared__ float wsum[16];
  if ((t & 63) == 0) wsum[t >> 6] = acc;
  __syncthreads();
  if (t == 0) {
    float tot = 0.0f;
#pragma unroll
    for (int i = 0; i < 16; ++i) tot += wsum[i];
    out[0] = tot / (float)N;
  }
}

extern "C" void kernel_launch(void* const* d_in, const int* in_sizes, int n_in,
                              void* d_out, int out_size, void* d_ws, size_t ws_size,
                              hipStream_t stream) {
  const float* x = (const float*)d_in[0];
  float* rowsum = (float*)d_ws;
  float* pos = rowsum + N;
  unsigned char* xn = (unsigned char*)(rowsum + 2 * N + 16);

  norm_kernel<<<N / 4, 256, 0, stream>>>(x, xn, rowsum);
  sim_kernel<<<NTILES, 256, 0, stream>>>(xn, rowsum, pos);
  loss_kernel<<<1, 1024, 0, stream>>>(rowsum, pos, (float*)d_out);
}

// Round 6
// 125.017 us; speedup vs baseline: 1.7774x; 1.0321x over previous
//
#include <hip/hip_runtime.h>
#include <hip/hip_bf16.h>

#define N 8192
#define D 768
#define TEMP_INV 20.0f
#define NTILES 2080   // 64x64 tile-grid upper triangle incl. diagonal

typedef __attribute__((ext_vector_type(4))) float f32x4;
typedef __attribute__((ext_vector_type(4))) int i32x4;
typedef __attribute__((ext_vector_type(8))) int i32x8;

#define SCALE1 0x7F7F7F7F  // e8m0 = 127 in all 4 bytes -> scale 1.0

// Workspace layout (floats):
//   [0,   N)     rowsum   (zeroed by norm_kernel)
//   [N,  2N)     pos      (fully written by sim_kernel diag tiles)
//   [2N, 2N+16)  pad
//   [2N+16, ...) xn fp8-e4m3 [N][768] bytes

// ---------------------------------------------------------------------------
// Kernel 1: row L2-normalize fp32 -> fp8 e4m3. One row per wave (4 rows/block).
__global__ __launch_bounds__(256) void norm_kernel(
    const float* __restrict__ x, unsigned char* __restrict__ xn,
    float* __restrict__ rowsum) {
  int t = threadIdx.x, w = t >> 6, lane = t & 63;
  int row = blockIdx.x * 4 + w;
  const float4* xr = (const float4*)(x + (size_t)row * D);
  float4 v[3];
  v[0] = xr[lane];
  v[1] = xr[lane + 64];
  v[2] = xr[lane + 128];
  float ss = 0.0f;
#pragma unroll
  for (int i = 0; i < 3; ++i)
    ss += v[i].x * v[i].x + v[i].y * v[i].y + v[i].z * v[i].z + v[i].w * v[i].w;
#pragma unroll
  for (int m = 32; m; m >>= 1) ss += __shfl_xor(ss, m);
  float inv = 1.0f / fmaxf(sqrtf(ss), 1e-8f);
  unsigned int* xo = (unsigned int*)(xn + (size_t)row * D);
#pragma unroll
  for (int i = 0; i < 3; ++i) {
    int p = __builtin_amdgcn_cvt_pk_fp8_f32(v[i].x * inv, v[i].y * inv, 0, false);
    p = __builtin_amdgcn_cvt_pk_fp8_f32(v[i].z * inv, v[i].w * inv, p, true);
    xo[lane + 64 * i] = p;
  }
  if (t < 4) rowsum[blockIdx.x * 4 + t] = 0.0f;
}

// ---------------------------------------------------------------------------
// Kernel 2: upper-triangle 128x128 tiles of S = Xn * Xn^T via MX-scaled fp8
// MFMA (K=128, scales=1.0 -> plain fp8 GEMM at 2x non-scaled rate).
//
// XCD-locality schedule: tiles enumerated supertile-major (8x8-tile
// supertiles, working set 16 panels = 1.5 MB < 4 MB per-XCD L2); global
// position p = 260*(blockIdx%8) + blockIdx/8 gives each XCD one contiguous
// 260-tile chunk (blockIdx%8 == XCD id, round-robin dispatch).
__global__ __launch_bounds__(256, 4) void sim_kernel(
    const unsigned char* __restrict__ xn, float* __restrict__ rowsum,
    float* __restrict__ pos) {
  // ---- tile decode: blockIdx -> XCD-chunk position -> supertile -> (bi,bj)
  static const short stbase[37] = {
      0, 36, 100, 164, 228, 292, 356, 420,
      484, 520, 584, 648, 712, 776, 840,
      904, 940, 1004, 1068, 1132, 1196,
      1260, 1296, 1360, 1424, 1488,
      1552, 1588, 1652, 1716,
      1780, 1816, 1880,
      1944, 1980,
      2044, 2080};
  static const char sti[36] = {0,0,0,0,0,0,0,0, 1,1,1,1,1,1,1, 2,2,2,2,2,2,
                               3,3,3,3,3, 4,4,4,4, 5,5,5, 6,6, 7};
  static const char stj[36] = {0,1,2,3,4,5,6,7, 1,2,3,4,5,6,7, 2,3,4,5,6,7,
                               3,4,5,6,7, 4,5,6,7, 5,6,7, 6,7, 7};
  int b = blockIdx.x;
  int p = 260 * (b & 7) + (b >> 3);
  int s = 0;
  while ((int)stbase[s + 1] <= p) ++s;
  int wofs = p - stbase[s];
  int SI = sti[s], SJ = stj[s];
  int bi, bj;
  if (SI == SJ) {  // diagonal supertile: triangular 8x8, counts 8,7,...,1
    int di = 0, cum = 0;
    while (wofs >= cum + (8 - di)) { cum += 8 - di; ++di; }
    bi = SI * 8 + di;
    bj = SI * 8 + di + (wofs - cum);
  } else {
    bi = SI * 8 + (wofs >> 3);
    bj = SJ * 8 + (wofs & 7);
  }

  __shared__ i32x4 As4[128 * 8];  // 128 rows x 8 16B-units = 16 KB
  __shared__ i32x4 Bs4[128 * 8];

  int t = threadIdx.x;
  int w = t >> 6, lane = t & 63;
  int q = lane >> 4, cl = lane & 15;
  int wm = w >> 1, wn = w & 1;

  f32x4 acc[4][4] = {};

  // staging: thread t fills physical unit (t&7) of row (t>>3)+32*rr; source
  // logical unit = (t&7) ^ (row&7); row&7 == (t>>3)&7 for all rr (32%8==0)
  int ulog = (((t & 7) ^ ((t >> 3) & 7))) * 16;
  const unsigned char* Ab = xn + (size_t)(bi * 128 + (t >> 3)) * D + ulog;
  const unsigned char* Bb = xn + (size_t)(bj * 128 + (t >> 3)) * D + ulog;

  // fragment reads: lane needs logical units 2q, 2q+1 of its row;
  // physical = logical ^ (row&7), row&7 == cl&7 (64,16 are 0 mod 8)
  int u0 = (2 * q) ^ (cl & 7);
  int u1 = u0 ^ 1;

  for (int kc = 0; kc < 6; ++kc) {
    int k0 = kc * 128;
#pragma unroll
    for (int rr = 0; rr < 4; ++rr) {
      __builtin_amdgcn_global_load_lds(
          (const __attribute__((address_space(1))) unsigned int*)(Ab + (size_t)(rr * 32) * D + k0),
          (__attribute__((address_space(3))) unsigned int*)(As4 + rr * 256 + t), 16, 0, 0);
      __builtin_amdgcn_global_load_lds(
          (const __attribute__((address_space(1))) unsigned int*)(Bb + (size_t)(rr * 32) * D + k0),
          (__attribute__((address_space(3))) unsigned int*)(Bs4 + rr * 256 + t), 16, 0, 0);
    }
    __syncthreads();

    union Frag { i32x8 v8; struct { i32x4 lo, hi; } pr; };
    Frag a[4], bb[4];
#pragma unroll
    for (int m = 0; m < 4; ++m) {
      int rowb = (wm * 64 + m * 16 + cl) * 8;
      a[m].pr.lo = As4[rowb + u0];
      a[m].pr.hi = As4[rowb + u1];
    }
#pragma unroll
    for (int n = 0; n < 4; ++n) {
      int rowb = (wn * 64 + n * 16 + cl) * 8;
      bb[n].pr.lo = Bs4[rowb + u0];
      bb[n].pr.hi = Bs4[rowb + u1];
    }
#pragma unroll
    for (int m = 0; m < 4; ++m)
#pragma unroll
      for (int n = 0; n < 4; ++n)
        acc[m][n] = __builtin_amdgcn_mfma_scale_f32_16x16x128_f8f6f4(
            a[m].v8, bb[n].v8, acc[m][n], 0, 0, 0, SCALE1, 0, SCALE1);
    __syncthreads();
  }

  // Epilogue. C/D layout: col = lane&15, row = (lane>>4)*4 + reg (shape-det.).
  int gi0 = bi * 128 + wm * 64;
  int gj0 = bj * 128 + wn * 64;

  float rowp[4][4] = {};
  float colp[4] = {};

  if (bi == bj) {
#pragma unroll
    for (int m = 0; m < 4; ++m)
#pragma unroll
      for (int n = 0; n < 4; ++n)
#pragma unroll
        for (int r = 0; r < 4; ++r) {
          float sv = acc[m][n][r];
          int row = gi0 + m * 16 + q * 4 + r;
          int col = gj0 + n * 16 + cl;
          float e = __expf(TEMP_INV * sv - 20.0f);
          if (col == row) e = 0.0f;
          if (col == (row ^ 1)) pos[row] = TEMP_INV * sv;
          rowp[m][r] += e;
        }
  } else {
#pragma unroll
    for (int m = 0; m < 4; ++m)
#pragma unroll
      for (int n = 0; n < 4; ++n)
#pragma unroll
        for (int r = 0; r < 4; ++r) {
          float e = __expf(TEMP_INV * acc[m][n][r] - 20.0f);
          rowp[m][r] += e;
          colp[n] += e;
        }
  }

#pragma unroll
  for (int m = 0; m < 4; ++m)
#pragma unroll
    for (int r = 0; r < 4; ++r) {
      float v = rowp[m][r];
      v += __shfl_xor(v, 1);
      v += __shfl_xor(v, 2);
      v += __shfl_xor(v, 4);
      v += __shfl_xor(v, 8);
      if (cl == 0) atomicAdd(&rowsum[gi0 + m * 16 + q * 4 + r], v);
    }
  if (bi != bj) {
#pragma unroll
    for (int n = 0; n < 4; ++n) {
      float v = colp[n];
      v += __shfl_xor(v, 16);
      v += __shfl_xor(v, 32);
      if (q == 0) atomicAdd(&rowsum[gj0 + n * 16 + cl], v);
    }
  }
}

// ---------------------------------------------------------------------------
// Kernel 3: loss = mean_i (20 + log(rowsum[i]) - pos[i]); one 1024-thread block
__global__ __launch_bounds__(1024) void loss_kernel(
    const float* __restrict__ rowsum, const float* __restrict__ pos,
    float* __restrict__ out) {
  int t = threadIdx.x;
  const float4* r4 = (const float4*)rowsum;
  const float4* p4 = (const float4*)pos;
  float acc = 0.0f;
#pragma unroll
  for (int it = 0; it < 2; ++it) {
    int i = t + it * 1024;
    float4 r = r4[i], pp = p4[i];
    acc += 80.0f + __logf(r.x) + __logf(r.y) + __logf(r.z) + __logf(r.w)
           - pp.x - pp.y - pp.z - pp.w;
  }
#pragma unroll
  for (int m = 32; m; m >>= 1) acc += __shfl_xor(acc, m);
  __shared__ float wsum[16];
  if ((t & 63) == 0) wsum[t >> 6] = acc;
  __syncthreads();
  if (t == 0) {
    float tot = 0.0f;
#pragma unroll
    for (int i = 0; i < 16; ++i) tot += wsum[i];
    out[0] = tot / (float)N;
  }
}

extern "C" void kernel_launch(void* const* d_in, const int* in_sizes, int n_in,
                              void* d_out, int out_size, void* d_ws, size_t ws_size,
                              hipStream_t stream) {
  const float* x = (const float*)d_in[0];
  float* rowsum = (float*)d_ws;
  float* pos = rowsum + N;
  unsigned char* xn = (unsigned char*)(rowsum + 2 * N + 16);

  norm_kernel<<<N / 4, 256, 0, stream>>>(x, xn, rowsum);
  sim_kernel<<<NTILES, 256, 0, stream>>>(xn, rowsum, pos);
  loss_kernel<<<1, 1024, 0, stream>>>(rowsum, pos, (float*)d_out);
}